// Round 2
// baseline (7680.767 us; speedup 1.0000x reference)
//
#include <hip/hip_runtime.h>

typedef unsigned short u16;
typedef unsigned int   u32;

typedef __bf16 bf16x8 __attribute__((ext_vector_type(8)));
typedef float  f32x4  __attribute__((ext_vector_type(4)));
typedef u32    u32x4  __attribute__((ext_vector_type(4)));

#define B_    32
#define S_    512
#define I_    512
#define H_    1024
#define NBLK  128                 // blocks; each owns H_/NBLK = 8 hidden units
#define HU    8
#define SLOT_ELEMS (B_ * H_)      // one h snapshot: 32768 u16 = 64 KB
// bf16 NaN pair. h = o*tanh(c) is always finite => bf16bits(h) != 0x7FC0, so
// this pattern can never be produced by a payload store. Per-DWORD check is
// tear-proof (dword store atomicity is HW-guaranteed even if dwordx4 split).
#define POISON 0x7FC07FC0u

__device__ __forceinline__ u16 bf16bits(float f) {
    __bf16 b = (__bf16)f;                       // HW RNE convert on gfx950
    return __builtin_bit_cast(u16, b);
}
__device__ __forceinline__ float sigmoid_(float x) {
    return 1.0f / (1.0f + __expf(-x));
}
__device__ __forceinline__ float tanh_(float x) {
    return 2.0f / (1.0f + __expf(-2.0f * x)) - 1.0f;
}

// Persistent LSTM (fp32 I/O, bf16 MFMA compute).
// RING MODE: barrier-free self-synchronizing dataflow. h values are the sync
// tokens: ring slots are pre-poisoned with bf16-NaN pairs (impossible payload);
// readers poll fragments directly (sc0 sc1, IC-coherent) and retry only stale
// ones. No flags, no vmcnt drain before publish, no release barrier, no global
// max-skew per step — blocks free-run coupled only by true data dependencies.
// Ordering: each block poisons its OWN output regions of slots 1..512, then
// one vmcnt(0) drain, then enters the loop. A reader touches slot t (t>=1)
// only after consuming every producer's slot t-1 payload, which was stored
// after that producer's drain => reader can only see poison-or-payload.
// Slot 0 is never read: h0 = 0 => the t=0 step skips the h@U phase entirely.
// FALLBACK MODE (small ws): previous flag-barrier protocol, unchanged.
__global__ void __launch_bounds__(256, 1)
lstm_kernel(const float* __restrict__ X,
            const float* __restrict__ w_i, const float* __restrict__ u_i, const float* __restrict__ b_i,
            const float* __restrict__ w_f, const float* __restrict__ u_f, const float* __restrict__ b_f,
            const float* __restrict__ w_c, const float* __restrict__ u_c, const float* __restrict__ b_c,
            const float* __restrict__ w_o, const float* __restrict__ u_o, const float* __restrict__ b_o,
            float* __restrict__ out, u16* __restrict__ hbuf,
            u32* __restrict__ slots, int ring)
{
    __shared__ float gbuf[32 * 33];   // raw gates, +1 col pad

    const int tid  = threadIdx.x;
    const int bid  = blockIdx.x;
    const int wave = tid >> 6;
    const int lane = tid & 63;
    const int rt   = wave >> 1;       // row tile (batch 16*rt..)
    const int ct   = wave & 1;        // col tile (gate cols 16*ct..)
    const int quad = lane >> 4;
    const int l16  = lane & 15;
    const int hu0  = bid * HU;

    // ---- ring mode: poison own region of slots 1..512 (stores fly during
    // the long strided B-fragment load below; one drain covers both) ----
    if (ring) {
        u32x4 pz; pz[0] = pz[1] = pz[2] = pz[3] = POISON;
        const int sl = tid >> 5, ln = tid & 31;   // 8 slots x 32 lanes per iter
        for (int i = 0; i < 64; ++i) {
            int s = 1 + i * 8 + sl;               // slots 1..512
            u32* pp = (u32*)hbuf + (size_t)s * (SLOT_ELEMS / 2) + bid * 128 + ln * 4;
            asm volatile("global_store_dwordx4 %0, %1, off sc0 sc1"
                         :: "v"(pp), "v"(pz) : "memory");
        }
    }

    // ---- B-operand fragments into registers (once), fp32 -> bf16 ----
    // block-local gate col: 0..31 = gate g (i,f,c,o) * 8 + unit u
    const int col = ct * 16 + l16;
    const int g   = col >> 3;
    const int u   = col & 7;
    const float* Ucol = ((g == 0) ? u_i : (g == 1) ? u_f : (g == 2) ? u_c : u_o) + hu0 + u;
    const float* Wcol = ((g == 0) ? w_i : (g == 1) ? w_f : (g == 2) ? w_c : w_o) + hu0 + u;

    bf16x8 bfr[48];                   // B[k = kb*32 + quad*8 + j][col]
    #pragma unroll
    for (int kb = 0; kb < 32; ++kb) { // K 0..1023: U rows
        #pragma unroll
        for (int j = 0; j < 8; ++j) {
            int k = kb * 32 + quad * 8 + j;
            bfr[kb][j] = (__bf16)Ucol[k * H_];
        }
    }
    #pragma unroll
    for (int kb = 32; kb < 48; ++kb) { // K 1024..1535: W rows
        #pragma unroll
        for (int j = 0; j < 8; ++j) {
            int k = kb * 32 + quad * 8 + j - 1024;
            bfr[kb][j] = (__bf16)Wcol[k * H_];
        }
    }

    // ---- update-phase ownership: thread -> (batch ub, unit uu) ----
    const int ub   = tid >> 3;        // batch 0..31
    const int uu   = tid & 7;         // unit  0..7
    const int unit = hu0 + uu;

    if (!ring) {
        // fallback: h0 = 0 into slot 0 (flag barrier orders it)
        if ((uu & 1) == 0) {
            u32* p0 = (u32*)hbuf + ((bid * 256 + ub * 8 + uu) >> 1);
            __hip_atomic_store(p0, 0u, __ATOMIC_RELAXED, __HIP_MEMORY_SCOPE_AGENT);
        }
    }

    // drain poison (+ B-frag loads) before ANY payload store can issue
    asm volatile("s_waitcnt vmcnt(0)" ::: "memory");

    const float bia = b_i[unit];
    const float bif = b_f[unit];
    const float bic = b_c[unit];
    const float bio = b_o[unit];
    float cstate = 0.0f;
    float h_prev = 0.0f;

    const int    arow = rt * 16 + l16;                    // batch row this lane feeds to A
    const float* xrow = X + arow * (S_ * I_) + quad * 8;  // A[m][k]: m=lane&15(+16rt), k=quad*8+j

    if (ring) {
        for (int t = 0; t < S_; ++t) {
            // gbuf rotate only: raw barrier, NO vmcnt drain (h store ack is
            // off the critical path — readers sync on data, not on us)
            asm volatile("s_barrier" ::: "memory");

            if (t)
                out[ub * (S_ * H_) + (t - 1) * H_ + unit] = h_prev;

            // issue all 32 h(t-1) fragment loads early; their IC latency
            // hides under x@W below (compiler waits over-drain: acceptable)
            u32x4 d[32];
            const u32x4* hq = (const u32x4*)((const u32*)hbuf
                               + (size_t)t * (SLOT_ELEMS / 2) + arow * 4 + quad * 128);
            if (t) {
                #pragma unroll
                for (int kb = 0; kb < 32; ++kb)
                    asm volatile("global_load_dwordx4 %0, %1, off sc0 sc1"
                                 : "=v"(d[kb]) : "v"(hq + kb * 128));
            }

            // ---- x_t @ W: h-independent ----
            f32x4 accW = {0.f, 0.f, 0.f, 0.f};
            const float* xk = xrow + t * I_;
            #pragma unroll
            for (int kb = 0; kb < 16; ++kb) {
                f32x4 lo = *(const f32x4*)(xk + kb * 32);
                f32x4 hi = *(const f32x4*)(xk + kb * 32 + 4);
                bf16x8 a;
                a[0] = (__bf16)lo[0]; a[1] = (__bf16)lo[1];
                a[2] = (__bf16)lo[2]; a[3] = (__bf16)lo[3];
                a[4] = (__bf16)hi[0]; a[5] = (__bf16)hi[1];
                a[6] = (__bf16)hi[2]; a[7] = (__bf16)hi[3];
                accW = __builtin_amdgcn_mfma_f32_16x16x32_bf16(a, bfr[32 + kb], accW, 0, 0, 0);
            }

            // ---- h(t-1) @ U: check fragments, re-poll stragglers only ----
            f32x4 acc = accW;
            if (t) {
                f32x4 acc1 = {0.f, 0.f, 0.f, 0.f};
                asm volatile("s_waitcnt vmcnt(0)" ::: "memory");
                #pragma unroll
                for (int kb = 0; kb < 16; ++kb) {
                    while ((d[kb][0] == POISON) | (d[kb][1] == POISON) |
                           (d[kb][2] == POISON) | (d[kb][3] == POISON)) {
                        asm volatile("global_load_dwordx4 %0, %1, off sc0 sc1\n\t"
                                     "s_waitcnt vmcnt(0)"
                                     : "=v"(d[kb]) : "v"(hq + kb * 128) : "memory");
                    }
                    acc = __builtin_amdgcn_mfma_f32_16x16x32_bf16(
                              __builtin_bit_cast(bf16x8, d[kb]), bfr[kb], acc, 0, 0, 0);
                    const int kc = kb + 16;
                    while ((d[kc][0] == POISON) | (d[kc][1] == POISON) |
                           (d[kc][2] == POISON) | (d[kc][3] == POISON)) {
                        asm volatile("global_load_dwordx4 %0, %1, off sc0 sc1\n\t"
                                     "s_waitcnt vmcnt(0)"
                                     : "=v"(d[kc]) : "v"(hq + kc * 128) : "memory");
                    }
                    acc1 = __builtin_amdgcn_mfma_f32_16x16x32_bf16(
                              __builtin_bit_cast(bf16x8, d[kc]), bfr[kc], acc1, 0, 0, 0);
                }
                acc += acc1;
            }

            // C/D layout: D[row = quad*4 + r][col = lane&15] (+16 per tile)
            {
                const int r0 = rt * 16 + quad * 4;
                #pragma unroll
                for (int r = 0; r < 4; ++r)
                    gbuf[(r0 + r) * 33 + col] = acc[r];
            }
            __syncthreads();

            // gates -> c,h update (c stays in an fp32 register all 512 steps)
            {
                float gi = gbuf[ub * 33 + uu]      + bia;
                float gf = gbuf[ub * 33 + 8 + uu]  + bif;
                float gc = gbuf[ub * 33 + 16 + uu] + bic;
                float go = gbuf[ub * 33 + 24 + uu] + bio;
                float it  = sigmoid_(gi);
                float ft  = sigmoid_(gf);
                float ctl = tanh_(gc);
                float ot  = sigmoid_(go);
                cstate = ft * cstate + it * ctl;
                float h = ot * tanh_(cstate);
                h_prev = h;

                // pack 8 units (one batch row) -> one dwordx4 payload store;
                // this store IS the sync token for step t+1 readers
                float hnb = __shfl_xor(h, 1);
                u32 pk = (u32)bf16bits(h) | ((u32)bf16bits(hnb) << 16);
                u32 p1 = __shfl_down(pk, 2);
                u32 p2 = __shfl_down(pk, 4);
                u32 p3 = __shfl_down(pk, 6);
                if (uu == 0) {
                    u32* wp = (u32*)hbuf + (size_t)(t + 1) * (SLOT_ELEMS / 2)
                              + bid * 128 + ub * 4;
                    u32x4 q; q[0] = pk; q[1] = p1; q[2] = p2; q[3] = p3;
                    asm volatile("global_store_dwordx4 %0, %1, off sc0 sc1"
                                 :: "v"(wp), "v"(q) : "memory");
                }
            }
        }
    } else {
        // ================= fallback: flag-barrier protocol =================
        for (int t = 0; t < S_; ++t) {
            __syncthreads();
            if (tid == 0)
                __hip_atomic_store(&slots[bid], (u32)(t + 1),
                                   __ATOMIC_RELAXED, __HIP_MEMORY_SCOPE_AGENT);

            if (t)
                out[ub * (S_ * H_) + (t - 1) * H_ + unit] = h_prev;

            f32x4 accW = {0.f, 0.f, 0.f, 0.f};
            const float* xk = xrow + t * I_;
            #pragma unroll
            for (int kb = 0; kb < 16; ++kb) {
                f32x4 lo = *(const f32x4*)(xk + kb * 32);
                f32x4 hi = *(const f32x4*)(xk + kb * 32 + 4);
                bf16x8 a;
                a[0] = (__bf16)lo[0]; a[1] = (__bf16)lo[1];
                a[2] = (__bf16)lo[2]; a[3] = (__bf16)lo[3];
                a[4] = (__bf16)hi[0]; a[5] = (__bf16)hi[1];
                a[6] = (__bf16)hi[2]; a[7] = (__bf16)hi[3];
                accW = __builtin_amdgcn_mfma_f32_16x16x32_bf16(a, bfr[32 + kb], accW, 0, 0, 0);
            }

            if (tid < 32) {
                const u32* sp = slots + (tid << 2);
                const int target = t + 1;
                for (;;) {
                    u32x4 v;
                    asm volatile("global_load_dwordx4 %0, %1, off sc0 sc1\n\t"
                                 "s_waitcnt vmcnt(0)"
                                 : "=v"(v) : "v"(sp) : "memory");
                    if ((int)v[0] >= target && (int)v[1] >= target &&
                        (int)v[2] >= target && (int)v[3] >= target) break;
                }
            }
            asm volatile("s_barrier" ::: "memory");

            const int rdslot = t & 1;
            f32x4 acc = accW;
            const u32* hb32 = (const u32*)(hbuf + (size_t)rdslot * SLOT_ELEMS)
                              + (arow * 4 + quad * 128);
            #pragma unroll
            for (int kb = 0; kb < 32; ++kb) {
                union { u32 dd[4]; bf16x8 v; } cv;
                #pragma unroll
                for (int w = 0; w < 4; ++w)
                    cv.dd[w] = __hip_atomic_load(hb32 + kb * 512 + w,
                                                 __ATOMIC_RELAXED, __HIP_MEMORY_SCOPE_AGENT);
                acc = __builtin_amdgcn_mfma_f32_16x16x32_bf16(cv.v, bfr[kb], acc, 0, 0, 0);
            }

            {
                const int r0 = rt * 16 + quad * 4;
                #pragma unroll
                for (int r = 0; r < 4; ++r)
                    gbuf[(r0 + r) * 33 + col] = acc[r];
            }
            __syncthreads();

            {
                float gi = gbuf[ub * 33 + uu]      + bia;
                float gf = gbuf[ub * 33 + 8 + uu]  + bif;
                float gc = gbuf[ub * 33 + 16 + uu] + bic;
                float go = gbuf[ub * 33 + 24 + uu] + bio;
                float it  = sigmoid_(gi);
                float ft  = sigmoid_(gf);
                float ctl = tanh_(gc);
                float ot  = sigmoid_(go);
                cstate = ft * cstate + it * ctl;
                float h = ot * tanh_(cstate);
                h_prev = h;

                float hnb = __shfl_xor(h, 1);
                u32 pk = (u32)bf16bits(h) | ((u32)bf16bits(hnb) << 16);
                u32 p1 = __shfl_down(pk, 2);
                u32 p2 = __shfl_down(pk, 4);
                u32 p3 = __shfl_down(pk, 6);
                if (uu == 0) {
                    const int wrslot = (t + 1) & 1;
                    u32* wp = (u32*)hbuf + (size_t)wrslot * (SLOT_ELEMS / 2)
                              + bid * 128 + ub * 4;
                    u32x4 q; q[0] = pk; q[1] = p1; q[2] = p2; q[3] = p3;
                    asm volatile("global_store_dwordx4 %0, %1, off sc0 sc1"
                                 :: "v"(wp), "v"(q) : "memory");
                }
            }
        }
    }

    // tail: last hidden row + finals (kernel-end flush publishes to host)
    out[ub * (S_ * H_) + (S_ - 1) * H_ + unit] = h_prev;
    out[B_ * S_ * H_ + ub * H_ + unit] = h_prev;                  // h_t
    out[B_ * S_ * H_ + B_ * H_ + ub * H_ + unit] = cstate;        // c_t
}

extern "C" void kernel_launch(void* const* d_in, const int* in_sizes, int n_in,
                              void* d_out, int out_size, void* d_ws, size_t ws_size,
                              hipStream_t stream) {
    const float* X   = (const float*)d_in[0];
    const float* w_i = (const float*)d_in[1];
    const float* u_i = (const float*)d_in[2];
    const float* b_i = (const float*)d_in[3];
    const float* w_f = (const float*)d_in[4];
    const float* u_f = (const float*)d_in[5];
    const float* b_f = (const float*)d_in[6];
    const float* w_c = (const float*)d_in[7];
    const float* u_c = (const float*)d_in[8];
    const float* b_c = (const float*)d_in[9];
    const float* w_o = (const float*)d_in[10];
    const float* u_o = (const float*)d_in[11];
    const float* b_o = (const float*)d_in[12];
    float* out = (float*)d_out;

    // ws layout: ring of (S_+1) h slots (64 KB each) if it fits, else 2 slots
    // (alternating, flag-barrier fallback); then 128 packed barrier slot dwords.
    const size_t ring_bytes = (size_t)(S_ + 1) * SLOT_ELEMS * sizeof(u16); // 33.6 MB
    const size_t fb_bytes   = (size_t)2 * SLOT_ELEMS * sizeof(u16);        // 128 KB
    int ring = (ws_size >= ring_bytes + 1024) ? 1 : 0;
    size_t slots_off = ring ? ring_bytes : fb_bytes;

    u16* hbuf  = (u16*)d_ws;
    u32* slots = (u32*)((char*)d_ws + slots_off);

    hipLaunchKernelGGL(lstm_kernel, dim3(NBLK), dim3(256), 0, stream,
                       X, w_i, u_i, b_i, w_f, u_f, b_f, w_c, u_c, b_c,
                       w_o, u_o, b_o, out, hbuf, slots, ring);
}

// Round 4
// 2991.892 us; speedup vs baseline: 2.5672x; 2.5672x over previous
//
#include <hip/hip_runtime.h>

typedef unsigned short u16;
typedef unsigned int   u32;

typedef __bf16 bf16x8 __attribute__((ext_vector_type(8)));
typedef float  f32x4  __attribute__((ext_vector_type(4)));
typedef u32    u32x4  __attribute__((ext_vector_type(4)));

#define B_ 32
#define S_ 512
#define I_ 512
#define H_ 1024
#define NB 64              // recurrent blocks; each owns H_/NB*4... 16 units
#define UB 16              // units per block
#define CB 64              // gate-cols per block (16 units x 4 gates)

#define XBF_U16   (S_ * B_ * I_)           // 8,388,608 u16 = 16.8 MB
#define HSLOT_B   65536                    // one h slot: [32 batch][1024 unit] bf16

__device__ __forceinline__ u16 bf16bits(float f) {
    __bf16 b = (__bf16)f;                  // HW RNE convert
    return __builtin_bit_cast(u16, b);
}
__device__ __forceinline__ float sigmoid_(float x) { return 1.0f / (1.0f + __expf(-x)); }
__device__ __forceinline__ float tanh_(float x)    { return 2.0f / (1.0f + __expf(-2.0f * x)) - 1.0f; }

// ============================================================================
// Kernel A: X [32][512][512] fp32  ->  Xbf [t][batch][512] bf16  (t-major).
// Stream-ordered before the recurrent kernel; removes the per-step fp32 load
// + cvt VALU storm from the recurrence. Plain cached loads/stores (kernel
// boundary release/acquire makes them visible to kernel B).
// ============================================================================
__global__ void __launch_bounds__(256)
xcvt(const float* __restrict__ X, u16* __restrict__ xbf)
{
    const int t = blockIdx.x, tid = threadIdx.x;
    #pragma unroll 4
    for (int b = 0; b < B_; ++b) {
        float2 v = *(const float2*)(X + (size_t)b * (S_ * I_) + (size_t)t * I_ + tid * 2);
        u32 pk = (u32)bf16bits(v.x) | ((u32)bf16bits(v.y) << 16);
        *(u32*)(xbf + (size_t)t * (B_ * I_) + b * I_ + tid * 2) = pk;
    }
}

// ============================================================================
// Kernel B: persistent recurrence, 64 blocks x 512 threads (trivially
// co-resident; no helpers, no placement assumptions, always device scope).
// Block owns 16 hidden units (64 gate-cols). Per step:
//   [issue x prefetch (plain, cached)] -> rendezvous: wave0 polls 64 flags
//   (sc0 sc1, monotonic, poison-safe signed compare) -> s_barrier ->
//   stage h(t) 64KB global->LDS (sc0 sc1, XOR-swizzled) + x 32KB ->
//   syncthreads -> 8 waves (2 colgrp x 4 K-quarter) x 48 MFMA, partials to
//   4 disjoint LDS gbufs (no atomics) -> syncthreads -> update (1 unit x
//   1 batch per thread, c in register) -> h store (sc0 sc1) -> vmcnt drain
//   -> s_barrier -> tid0 flag=t+1 -> out stores (off the drain path).
// t=0: h region zero-filled in LDS, no rendezvous (h0 = 0, slot never read).
// U+W fragments: 96 VGPR/lane, loaded once (register floor for 64 cols).
// ============================================================================
__global__ void __launch_bounds__(512, 2)
lstm_rec(const u16* __restrict__ xbf,
         const float* __restrict__ u_i, const float* __restrict__ b_i,
         const float* __restrict__ u_f, const float* __restrict__ b_f,
         const float* __restrict__ u_c, const float* __restrict__ b_c,
         const float* __restrict__ u_o, const float* __restrict__ b_o,
         const float* __restrict__ w_i, const float* __restrict__ w_f,
         const float* __restrict__ w_c, const float* __restrict__ w_o,
         float* __restrict__ out, u16* __restrict__ hsl, u32* __restrict__ flags)
{
    __shared__ __align__(16) char  hx[32 * 3072];      // [batch][2048B h | 1024B x]
    __shared__ __align__(16) float gb[4][32][68];      // per-K-quarter gate partials

    const int tid  = threadIdx.x;
    const int bid  = blockIdx.x;
    const int wave = tid >> 6;
    const int lane = tid & 63;
    const int quad = lane >> 4;
    const int l16  = lane & 15;
    const int cg   = wave & 1;        // col group: 32 cols
    const int kq   = wave >> 1;       // K quarter: 12 kb of K=32 (h kb 0..31, x kb 32..47)

    // ---- B fragments (U then W), 2 colsets x 12 kb = 96 VGPRs, loaded once
    bf16x8 bfr[2][12];
    #pragma unroll
    for (int cs = 0; cs < 2; ++cs) {
        const int gc = bid * CB + cg * 32 + cs * 16 + l16;
        const int ug = gc >> 2, g = gc & 3;
        const float* Up = ((g == 0) ? u_i : (g == 1) ? u_f : (g == 2) ? u_c : u_o) + ug;
        const float* Wp = ((g == 0) ? w_i : (g == 1) ? w_f : (g == 2) ? w_c : w_o) + ug;
        #pragma unroll
        for (int kb = 0; kb < 12; ++kb) {
            const int kbg = kq * 12 + kb;
            #pragma unroll
            for (int j = 0; j < 8; ++j) {
                const int k = kbg * 32 + quad * 8 + j;
                bfr[cs][kb][j] = (k < 1024) ? (__bf16)Up[(size_t)k * H_]
                                            : (__bf16)Wp[(size_t)(k - 1024) * H_];
            }
        }
    }

    // ---- staging map: thread -> (row srow, 128B h chunk + 64B x chunk sch)
    // row = tid&31 so a granule's 8 writers span 8 rows -> conflict-free with key
    const int srow = tid & 31;
    const int sch  = tid >> 5;                       // 0..15
    const int skey = (srow & 7) << 4;
    char* sdst = hx + srow * 3072;
    const int akey = (l16 & 7) << 4;

    // ---- update map: thread -> (batch ub2, unit uq)
    const int ub2  = tid >> 4;
    const int uq   = tid & 15;
    const int unit = bid * UB + uq;
    const float bia = b_i[unit], bif = b_f[unit], bic = b_c[unit], bio = b_o[unit];
    float cst = 0.0f;

    for (int t = 0; t < S_; ++t) {
        // x prefetch (plain, cached; overlaps the rendezvous poll)
        const u32x4* xsrc = (const u32x4*)(xbf + (size_t)t * (B_ * I_) + srow * I_ + sch * 32);
        u32x4 xv0 = xsrc[0], xv1 = xsrc[1], xv2 = xsrc[2], xv3 = xsrc[3];

        if (t) {
            // rendezvous: all 64 flags >= t  (h(t) published, h(t-1) consumed)
            if (wave == 0) {
                const u32* fp = flags + lane * 16;   // 64B stride
                u32 v;
                do {
                    asm volatile("global_load_dword %0, %1, off sc0 sc1\n\t"
                                 "s_waitcnt vmcnt(0)"
                                 : "=v"(v) : "v"(fp) : "memory");
                } while ((int)v < t);                 // 0xAAAAAAAA poison < 1
            }
            asm volatile("s_barrier" ::: "memory");

            // stage h(t): 128B/thread, IC-coherent, swizzled into LDS
            const char* hsrc = (const char*)hsl + (size_t)(t & 1) * HSLOT_B
                               + srow * 2048 + sch * 128;
            u32x4 h0, h1, h2, h3, h4, h5, h6, h7;
            asm volatile(
                "global_load_dwordx4 %0, %8, off sc0 sc1\n\t"
                "global_load_dwordx4 %1, %8, off offset:16 sc0 sc1\n\t"
                "global_load_dwordx4 %2, %8, off offset:32 sc0 sc1\n\t"
                "global_load_dwordx4 %3, %8, off offset:48 sc0 sc1\n\t"
                "global_load_dwordx4 %4, %8, off offset:64 sc0 sc1\n\t"
                "global_load_dwordx4 %5, %8, off offset:80 sc0 sc1\n\t"
                "global_load_dwordx4 %6, %8, off offset:96 sc0 sc1\n\t"
                "global_load_dwordx4 %7, %8, off offset:112 sc0 sc1\n\t"
                "s_waitcnt vmcnt(0)"
                : "=&v"(h0), "=&v"(h1), "=&v"(h2), "=&v"(h3),
                  "=&v"(h4), "=&v"(h5), "=&v"(h6), "=&v"(h7)
                : "v"(hsrc) : "memory");
            *(u32x4*)(sdst + ((sch * 128 +   0) ^ skey)) = h0;
            *(u32x4*)(sdst + ((sch * 128 +  16) ^ skey)) = h1;
            *(u32x4*)(sdst + ((sch * 128 +  32) ^ skey)) = h2;
            *(u32x4*)(sdst + ((sch * 128 +  48) ^ skey)) = h3;
            *(u32x4*)(sdst + ((sch * 128 +  64) ^ skey)) = h4;
            *(u32x4*)(sdst + ((sch * 128 +  80) ^ skey)) = h5;
            *(u32x4*)(sdst + ((sch * 128 +  96) ^ skey)) = h6;
            *(u32x4*)(sdst + ((sch * 128 + 112) ^ skey)) = h7;
        } else {
            // h0 = 0: zero-fill h region, run the identical MFMA loop
            u32x4 z = {0u, 0u, 0u, 0u};
            #pragma unroll
            for (int i = 0; i < 8; ++i)
                *(u32x4*)(sdst + ((sch * 128 + i * 16) ^ skey)) = z;
        }
        // stage x (64B/thread)
        *(u32x4*)(sdst + ((2048 + sch * 64 +  0) ^ skey)) = xv0;
        *(u32x4*)(sdst + ((2048 + sch * 64 + 16) ^ skey)) = xv1;
        *(u32x4*)(sdst + ((2048 + sch * 64 + 32) ^ skey)) = xv2;
        *(u32x4*)(sdst + ((2048 + sch * 64 + 48) ^ skey)) = xv3;
        __syncthreads();

        // ---- MFMA: 12 kb x 2 row-tiles x 2 colsets = 48 per wave
        f32x4 a00 = {0.f, 0.f, 0.f, 0.f}, a01 = {0.f, 0.f, 0.f, 0.f};
        f32x4 a10 = {0.f, 0.f, 0.f, 0.f}, a11 = {0.f, 0.f, 0.f, 0.f};
        #pragma unroll
        for (int kb = 0; kb < 12; ++kb) {
            const int off = (kq * 12 + kb) * 64 + quad * 16;   // h 0..2047, x 2048..3071 seamless
            bf16x8 A0 = *(const bf16x8*)(hx + l16 * 3072 + (off ^ akey));
            bf16x8 A1 = *(const bf16x8*)(hx + (16 + l16) * 3072 + (off ^ akey));
            a00 = __builtin_amdgcn_mfma_f32_16x16x32_bf16(A0, bfr[0][kb], a00, 0, 0, 0);
            a10 = __builtin_amdgcn_mfma_f32_16x16x32_bf16(A1, bfr[0][kb], a10, 0, 0, 0);
            a01 = __builtin_amdgcn_mfma_f32_16x16x32_bf16(A0, bfr[1][kb], a01, 0, 0, 0);
            a11 = __builtin_amdgcn_mfma_f32_16x16x32_bf16(A1, bfr[1][kb], a11, 0, 0, 0);
        }
        // partials to this K-quarter's gbuf (disjoint cells: (kq, colgrp) unique)
        #pragma unroll
        for (int r = 0; r < 4; ++r) {
            gb[kq][quad * 4 + r][cg * 32 + l16]           = a00[r];
            gb[kq][quad * 4 + r][cg * 32 + 16 + l16]      = a01[r];
            gb[kq][16 + quad * 4 + r][cg * 32 + l16]      = a10[r];
            gb[kq][16 + quad * 4 + r][cg * 32 + 16 + l16] = a11[r];
        }
        __syncthreads();

        // ---- update: 1 (batch, unit) per thread; c stays in register
        f32x4 s0 = *(const f32x4*)&gb[0][ub2][uq * 4];
        f32x4 s1 = *(const f32x4*)&gb[1][ub2][uq * 4];
        f32x4 s2 = *(const f32x4*)&gb[2][ub2][uq * 4];
        f32x4 s3 = *(const f32x4*)&gb[3][ub2][uq * 4];
        f32x4 sg = s0 + s1 + s2 + s3;                 // i,f,c,o pre-activations
        const float gi = sg[0] + bia, gf = sg[1] + bif;
        const float gc2 = sg[2] + bic, go = sg[3] + bio;
        cst = sigmoid_(gf) * cst + sigmoid_(gi) * tanh_(gc2);
        const float h = sigmoid_(go) * tanh_(cst);
        const float hn = __shfl_xor(h, 1);            // all lanes (no divergence)

        if ((tid & 1) == 0) {
            u32 pk = (u32)bf16bits(h) | ((u32)bf16bits(hn) << 16);
            char* hp = (char*)hsl + (size_t)((t + 1) & 1) * HSLOT_B + ub2 * 2048 + unit * 2;
            asm volatile("global_store_dword %0, %1, off sc0 sc1"
                         :: "v"(hp), "v"(pk) : "memory");
        }
        asm volatile("s_waitcnt vmcnt(0)" ::: "memory");
        asm volatile("s_barrier" ::: "memory");
        if (tid == 0) {
            u32* fp = flags + bid * 16;
            u32 fv = (u32)(t + 1);
            asm volatile("global_store_dword %0, %1, off sc0 sc1"
                         :: "v"(fp), "v"(fv) : "memory");
        }

        // ---- off the drain path: hidden_seq (+ finals) stores, plain cached
        if ((tid & 1) == 0) {
            float2 o2; o2.x = h; o2.y = hn;
            *(float2*)(out + (size_t)ub2 * (S_ * H_) + (size_t)t * H_ + unit) = o2;
        }
        if (t == S_ - 1) {
            const float cn = __shfl_xor(cst, 1);      // outside the tid&1 branch
            if ((tid & 1) == 0) {
                float2 hf; hf.x = h;   hf.y = hn;
                float2 cf; cf.x = cst; cf.y = cn;
                *(float2*)(out + (size_t)B_ * S_ * H_ + ub2 * H_ + unit) = hf;
                *(float2*)(out + (size_t)B_ * S_ * H_ + B_ * H_ + ub2 * H_ + unit) = cf;
            }
        }
    }
}

extern "C" void kernel_launch(void* const* d_in, const int* in_sizes, int n_in,
                              void* d_out, int out_size, void* d_ws, size_t ws_size,
                              hipStream_t stream) {
    const float* X   = (const float*)d_in[0];
    const float* w_i = (const float*)d_in[1];
    const float* u_i = (const float*)d_in[2];
    const float* b_i = (const float*)d_in[3];
    const float* w_f = (const float*)d_in[4];
    const float* u_f = (const float*)d_in[5];
    const float* b_f = (const float*)d_in[6];
    const float* w_c = (const float*)d_in[7];
    const float* u_c = (const float*)d_in[8];
    const float* b_c = (const float*)d_in[9];
    const float* w_o = (const float*)d_in[10];
    const float* u_o = (const float*)d_in[11];
    const float* b_o = (const float*)d_in[12];
    float* out = (float*)d_out;

    // ws: Xbf 16.8MB | 2 h slots 128KB | 64 flag cells (64B stride) 4KB
    u16* xbf   = (u16*)d_ws;
    u16* hsl   = (u16*)((char*)d_ws + (size_t)XBF_U16 * 2);
    u32* flags = (u32*)((char*)d_ws + (size_t)XBF_U16 * 2 + 2 * HSLOT_B);

    hipLaunchKernelGGL(xcvt, dim3(S_), dim3(256), 0, stream, X, xbf);
    hipLaunchKernelGGL(lstm_rec, dim3(NB), dim3(512), 0, stream,
                       xbf, u_i, b_i, u_f, b_f, u_c, b_c, u_o, b_o,
                       w_i, w_f, w_c, w_o, out, hsl, flags);
}